// Round 8
// baseline (4923.081 us; speedup 1.0000x reference)
//
#include <hip/hip_runtime.h>
#include <stdint.h>

#define TSTEPS 512
#define BATCH  64
#define HDIM   512
#define GATE   2048
#define ACTMAT (BATCH * HDIM)   // 32768 activations per timestep matrix
#define SENT   0xFFFFFFFFu      // f16 NaN-pair sentinel; |h|<1 so never produced
#define NWORK  128              // worker WGs (2 layers x 64 slices)
#define NWGTOT 512              // + 384 heater WGs -> 2 WGs/CU everywhere

typedef __attribute__((ext_vector_type(8))) _Float16 f16x8;
typedef __attribute__((ext_vector_type(4))) float f32x4;
typedef __attribute__((ext_vector_type(4))) uint32_t u32x4;

__device__ __forceinline__ unsigned short f2h(float f) {
  union { _Float16 h; unsigned short u; } v;
  v.h = (_Float16)f;                                 // RNE f32->f16
  return v.u;
}
__device__ __forceinline__ float fsigmoid(float x) {
  return 1.0f / (1.0f + __expf(-x));
}

// ---------------- pre-kernels ----------------

// Fill h histories with sentinel (t=0 slice = 0) and zero the done counter.
__global__ void init_h(unsigned short* h0, unsigned short* h1, int* ctrs) {
  size_t u = (size_t)blockIdx.x * blockDim.x + threadIdx.x;   // 16B unit index
  if (u < 16) ctrs[u] = 0;                           // re-zero EVERY launch (replay safe)
  u32x4 v;
  if (u < (ACTMAT * 2 / 16)) v = (u32x4){0u, 0u, 0u, 0u};
  else                       v = (u32x4){SENT, SENT, SENT, SENT};
  ((u32x4*)h0)[u] = v;
  ((u32x4*)h1)[u] = v;
}

__global__ void convert_x(const float* __restrict__ x, unsigned short* __restrict__ xh) {
  size_t i = (size_t)(blockIdx.x * blockDim.x + threadIdx.x) * 4;
  float4 v = *(const float4*)(x + i);
  ushort4 o = make_ushort4(f2h(v.x), f2h(v.y), f2h(v.z), f2h(v.w));
  *(ushort4*)(xh + i) = o;
}

// Fuse [Wi | Wh] into [GATE][1024], single f16 panel.
__global__ void split_w(const float* __restrict__ Wi, const float* __restrict__ Wh,
                        unsigned short* __restrict__ Wf) {
  int i = blockIdx.x * blockDim.x + threadIdx.x;     // over GATE*1024
  int G = i >> 10, k = i & 1023;
  float w = (k < 512) ? Wi[((size_t)G << 9) + k] : Wh[((size_t)G << 9) + (k - 512)];
  Wf[i] = f2h(w);
}

// ---------------- persistent recurrence kernel ----------------
// Workers (wg<128): EXACTLY the round-6 structure (proven 4719us PASS): 8 h-cols/WG,
// 32 gate rows, 64KB LDS f16 weights, transposed GEMM, zero-shuffle epilogue, packed
// 4B h-stores, sentinel data-as-flag protocol over sc0+sc1 (system-scope, MALL-coherent).
// NEW: workers run at s_setprio(2).
// Heaters (wg>=128): pure-VALU v_fma spin at prio 0 -> raises chip utilization so the
// DVFS governor lifts clocks out of the ~600MHz idle range (theory: the 3-4x gap between
// modeled ~2.5us and measured 9.2us step time is clock throttling at 4% utilization).
// Heaters poll a done counter (set by finishing workers) every 64 iters -> deterministic.

__global__ __launch_bounds__(256, 1)
void sublstm_persistent(const unsigned short* __restrict__ xh,
                        unsigned short* h0, unsigned short* h1,
                        const unsigned short* __restrict__ Wf0,
                        const unsigned short* __restrict__ Wf1,
                        const float* __restrict__ bi0, const float* __restrict__ bi1,
                        float* __restrict__ out, int* ctrs)
{
  __shared__ unsigned short wlds[32][1024];          // 64 KiB: [n][k] f16 bits

  const int wg    = blockIdx.x;
  const int tid   = threadIdx.x;

  if (wg >= NWORK) {
    // ---------------- heater ----------------
    float a = (float)(tid + 1) * 1.0e-3f;
    float bmul = 1.0000001f, cadd = 1.0e-7f;
    int it = 0;
    for (;;) {
      #pragma unroll
      for (int u = 0; u < 32; ++u)
        asm volatile("v_fma_f32 %0, %0, %1, %2" : "+v"(a) : "v"(bmul), "v"(cadd));
      if ((++it & 63) == 0) {
        if (__hip_atomic_load(ctrs, __ATOMIC_RELAXED, __HIP_MEMORY_SCOPE_AGENT) >= NWORK)
          break;
      }
    }
    asm volatile("" :: "v"(a));                      // keep the spin live
    return;
  }

  __builtin_amdgcn_s_setprio(2);                     // workers win SIMD arbitration

  const int layer = wg >> 6;
  const int slice = wg & 63;
  const int j0    = slice << 3;                      // first owned h-column
  const int lane  = tid & 63;
  const int wv    = tid >> 6;                        // wave 0..3 (b-tile)

  const unsigned short* Wf = layer ? Wf1 : Wf0;
  const float* bi = layer ? bi1 : bi0;

  // stage weight slice into LDS (16B units, unit index XOR-swizzled by n&15)
  for (int idx = tid; idx < 4096; idx += 256) {
    int n = (idx >> 7) & 31;                         // local gate row
    int u = idx & 127;                               // 16B unit within row
    int G = ((n & 3) << 9) + j0 + ((((n & 15) >> 2)) << 1) + (n >> 4);
    const unsigned short* s = Wf + ((size_t)G << 10) + ((size_t)u << 3);
    *(uint4*)&wlds[n][(u ^ (n & 15)) << 3] = *(const uint4*)s;
  }
  __syncthreads();

  const int c15 = lane & 15;
  const int g4  = lane >> 4;
  const int n0 = c15, n1 = 16 + c15;
  const int sw = c15;                                // XOR swizzle key
  const int b    = (wv << 4) + c15;                  // batch row this lane owns
  const int jcol0 = j0 + (g4 << 1);                  // even h-col; pair (jcol0, jcol0+1)
  const size_t arow = (size_t)b * HDIM;
  const size_t hoff0 = arow + jcol0;

  const float b00 = bi[jcol0],        b01 = bi[512 + jcol0];
  const float b02 = bi[1024 + jcol0], b03 = bi[1536 + jcol0];
  const float b10 = bi[jcol0 + 1],        b11 = bi[512 + jcol0 + 1];
  const float b12 = bi[1024 + jcol0 + 1], b13 = bi[1536 + jcol0 + 1];

  float c0 = 0.0f, c1 = 0.0f;                        // cell state, in regs all 512 steps

#define CONSUME(R, KK, UB) do {                                                        \
    f16x8 a = __builtin_bit_cast(f16x8, (R));                                          \
    int u_ = ((UB) + ((KK) << 2) + g4) ^ sw;                                           \
    f16x8 w0 = *(const f16x8*)&wlds[n0][u_ << 3];                                      \
    f16x8 w1 = *(const f16x8*)&wlds[n1][u_ << 3];                                      \
    acc0 = __builtin_amdgcn_mfma_f32_16x16x32_f16(w0, a, acc0, 0, 0, 0);               \
    acc1 = __builtin_amdgcn_mfma_f32_16x16x32_f16(w1, a, acc1, 0, 0, 0);               \
  } while (0)

#define CONSUME_ALL(P, UB)                                                             \
    CONSUME(P##0, 0, UB);  CONSUME(P##1, 1, UB);  CONSUME(P##2, 2, UB);                \
    CONSUME(P##3, 3, UB);  CONSUME(P##4, 4, UB);  CONSUME(P##5, 5, UB);                \
    CONSUME(P##6, 6, UB);  CONSUME(P##7, 7, UB);  CONSUME(P##8, 8, UB);                \
    CONSUME(P##9, 9, UB);  CONSUME(P##10, 10, UB); CONSUME(P##11, 11, UB);             \
    CONSUME(P##12, 12, UB); CONSUME(P##13, 13, UB); CONSUME(P##14, 14, UB);            \
    CONSUME(P##15, 15, UB)

#define LD1(R, OFFTOK, HP)                                                             \
    asm volatile("global_load_dwordx4 %0, %1, off " OFFTOK " sc0 sc1"                  \
                 : "=v"(R) : "v"(HP) : "memory")

#define ISSUE16(HP, P) do {                                                            \
    LD1(P##0, "", HP);            LD1(P##1, "offset:64", HP);                          \
    LD1(P##2, "offset:128", HP);  LD1(P##3, "offset:192", HP);                         \
    LD1(P##4, "offset:256", HP);  LD1(P##5, "offset:320", HP);                         \
    LD1(P##6, "offset:384", HP);  LD1(P##7, "offset:448", HP);                         \
    LD1(P##8, "offset:512", HP);  LD1(P##9, "offset:576", HP);                         \
    LD1(P##10, "offset:640", HP); LD1(P##11, "offset:704", HP);                        \
    LD1(P##12, "offset:768", HP); LD1(P##13, "offset:832", HP);                        \
    LD1(P##14, "offset:896", HP); LD1(P##15, "offset:960", HP);                        \
  } while (0)

#define BAD1(R) ((R[0] == SENT) | (R[1] == SENT) | (R[2] == SENT) | (R[3] == SENT))

#define VALIDATE(HP, P) do {                                                           \
    for (;;) {                                                                         \
      asm volatile("s_waitcnt vmcnt(0)" ::: "memory");                                 \
      __builtin_amdgcn_sched_barrier(0);                                               \
      int bad_ = BAD1(P##0) | BAD1(P##1) | BAD1(P##2) | BAD1(P##3) |                   \
                 BAD1(P##4) | BAD1(P##5) | BAD1(P##6) | BAD1(P##7) |                   \
                 BAD1(P##8) | BAD1(P##9) | BAD1(P##10) | BAD1(P##11) |                 \
                 BAD1(P##12) | BAD1(P##13) | BAD1(P##14) | BAD1(P##15);                \
      if (!__any(bad_)) break;                                                         \
      ISSUE16(HP, P);                                                                  \
    }                                                                                  \
    __builtin_amdgcn_sched_barrier(0);                                                 \
  } while (0)

// x half: plain cached loads (xh is read-only input, L2-resident per XCD)
#define KHALF_X(AP) do {                                                               \
    const unsigned short* ap_ = (AP) + arow + (g4 << 3);                               \
    _Pragma("unroll")                                                                  \
    for (int kk = 0; kk < 16; ++kk) {                                                  \
      u32x4 rr = *(const u32x4*)(ap_ + (kk << 5));                                     \
      CONSUME(rr, kk, 0);                                                              \
    }                                                                                  \
  } while (0)

#define EPILOGUE(T) do {                                                               \
    unsigned short* hn = (layer ? h1 : h0) + (size_t)((T) + 1) * ACTMAT;               \
    float gi0 = fsigmoid(acc0[0] + b00), go0 = fsigmoid(acc0[1] + b01);                \
    float gz0 = fsigmoid(acc0[2] + b02), gf0 = fsigmoid(acc0[3] + b03);                \
    c0 = c0 * gf0 + gz0 - gi0;                                                         \
    float hv0 = fsigmoid(c0) - go0;                                                    \
    float gi1 = fsigmoid(acc1[0] + b10), go1 = fsigmoid(acc1[1] + b11);                \
    float gz1 = fsigmoid(acc1[2] + b12), gf1 = fsigmoid(acc1[3] + b13);                \
    c1 = c1 * gf1 + gz1 - gi1;                                                         \
    float hv1 = fsigmoid(c1) - go1;                                                    \
    uint32_t hw = (uint32_t)f2h(hv0) | ((uint32_t)f2h(hv1) << 16);                     \
    __hip_atomic_store((uint32_t*)(hn + hoff0), hw, __ATOMIC_RELAXED,                  \
                       __HIP_MEMORY_SCOPE_AGENT);                                      \
    if (layer) {                                                                       \
      float* outp = out + (size_t)(T) * ACTMAT;                                        \
      *(float2*)(outp + hoff0) = make_float2(hv0, hv1);                                \
    }                                                                                  \
  } while (0)

  if (layer == 0) {
    for (int t = 0; t < TSTEPS; ++t) {
      f32x4 acc0 = {}, acc1 = {};
      u32x4 ra0, ra1, ra2, ra3, ra4, ra5, ra6, ra7,
            ra8, ra9, ra10, ra11, ra12, ra13, ra14, ra15;
      const unsigned short* hp = h0 + (size_t)t * ACTMAT + arow + (g4 << 3);
      ISSUE16(hp, ra);                               // speculative: hide RT under x-half
      KHALF_X(xh + (size_t)t * ACTMAT);              // independent work (32 MFMAs)
      VALIDATE(hp, ra);                              // sentinel check, re-issue if stale
      CONSUME_ALL(ra, 64);
      EPILOGUE(t);
    }
  } else {
    for (int t = 0; t < TSTEPS; ++t) {
      f32x4 acc0 = {}, acc1 = {};
      u32x4 ra0, ra1, ra2, ra3, ra4, ra5, ra6, ra7,
            ra8, ra9, ra10, ra11, ra12, ra13, ra14, ra15;
      u32x4 rb0, rb1, rb2, rb3, rb4, rb5, rb6, rb7,
            rb8, rb9, rb10, rb11, rb12, rb13, rb14, rb15;
      const unsigned short* hpA = h1 + (size_t)t * ACTMAT + arow + (g4 << 3);
      const unsigned short* hpB = h0 + (size_t)(t + 1) * ACTMAT + arow + (g4 << 3);
      ISSUE16(hpA, ra);                              // own h1[t]: almost always landed
      ISSUE16(hpB, rb);                              // layer0's h0[t+1]: the late one
      VALIDATE(hpA, ra);
      CONSUME_ALL(ra, 64);                           // 32 MFMAs hide hpB's round trip
      VALIDATE(hpB, rb);
      CONSUME_ALL(rb, 0);
      EPILOGUE(t);
    }
  }

  if (tid == 0) atomicAdd(ctrs, 1);                  // release heaters when all done
#undef CONSUME
#undef CONSUME_ALL
#undef LD1
#undef ISSUE16
#undef BAD1
#undef VALIDATE
#undef KHALF_X
#undef EPILOGUE
}

// ---------------- launch ----------------

extern "C" void kernel_launch(void* const* d_in, const int* in_sizes, int n_in,
                              void* d_out, int out_size, void* d_ws, size_t ws_size,
                              hipStream_t stream) {
  (void)in_sizes; (void)n_in; (void)out_size; (void)ws_size;
  const float* x   = (const float*)d_in[0];
  const float* Wi0 = (const float*)d_in[1];
  const float* bi0 = (const float*)d_in[2];
  const float* Wh0 = (const float*)d_in[3];
  const float* Wi1 = (const float*)d_in[4];
  const float* bi1 = (const float*)d_in[5];
  const float* Wh1 = (const float*)d_in[6];
  float* out = (float*)d_out;

  char* ws = (char*)d_ws;
  size_t off = 0;
  auto take = [&](size_t bytes) -> void* {
    void* p = ws + off;
    off += (bytes + 255) & ~(size_t)255;
    return p;
  };
  unsigned short* xh  = (unsigned short*)take((size_t)TSTEPS * ACTMAT * 2);        // 33.5 MB
  unsigned short* h0  = (unsigned short*)take((size_t)(TSTEPS + 1) * ACTMAT * 2);  // 33.6 MB
  unsigned short* h1  = (unsigned short*)take((size_t)(TSTEPS + 1) * ACTMAT * 2);  // 33.6 MB
  unsigned short* Wf0 = (unsigned short*)take((size_t)GATE * 1024 * 2);            // 4 MB
  unsigned short* Wf1 = (unsigned short*)take((size_t)GATE * 1024 * 2);            // 4 MB
  int* ctrs           = (int*)take(64);

  // (TSTEPS+1)*ACTMAT ushorts = 33,619,968 B per buffer -> 2,101,248 16B units
  init_h<<<dim3(8208), dim3(256), 0, stream>>>(h0, h1, ctrs);
  convert_x<<<dim3(16384), dim3(256), 0, stream>>>(x, xh);
  split_w<<<dim3(8192), dim3(256), 0, stream>>>(Wi0, Wh0, Wf0);
  split_w<<<dim3(8192), dim3(256), 0, stream>>>(Wi1, Wh1, Wf1);
  sublstm_persistent<<<dim3(NWGTOT), dim3(256), 0, stream>>>(
      xh, h0, h1, Wf0, Wf1, bi0, bi1, out, ctrs);
}